// Round 9
// baseline (593.402 us; speedup 1.0000x reference)
//
#include <hip/hip_runtime.h>
#include <hip/hip_bf16.h>

// LocalAttention B=4, L=2048, C=512, H=8, Dh=64 — round 9.
// proj/w_cvt/transpose: round-7 (gll staging) with manual-RNE pk2.
// attn: 256 thr, 4 waves x 32q, reg-prefetch K/V dbuf, no-max softmax,
//   shfl_xor P-exchange (no Ps LDS), manual pk2 (r8's __float22bfloat162_rn
//   was the VALU explosion: non-trivially-copyable temp at high reg pressure).
//   NEW: 2-way key-split across blocks (linear combine, valid because no-max
//   softmax) -> 1024 blocks -> 4 blocks/CU -> 4 waves/SIMD. Partial O (fp32,
//   [s][bh][d][q]) + l to ws; attn_reduce normalizes into ctx.
//   Host falls back to unsplit kernel if ws_size < 59 MB.

#define BB  4
#define LL  2048
#define CC  512
#define HH  8
#define DHH 64

typedef __attribute__((ext_vector_type(8)))  short bf16x8;   // 16 B
typedef __attribute__((ext_vector_type(4)))  short bf16x4;   // 8 B
typedef __attribute__((ext_vector_type(16))) float f32x16;   // MFMA C/D
typedef __attribute__((ext_vector_type(2)))  unsigned uint2v;
typedef __attribute__((ext_vector_type(4)))  unsigned uint4v;

using us = unsigned short;

#if __has_builtin(__builtin_amdgcn_exp2f)
#define EXP2(x) __builtin_amdgcn_exp2f(x)
#else
#define EXP2(x) __expf(0.6931471805599453f * (x))
#endif

__device__ __forceinline__ int swz(int r) { return (r + (r >> 3)) & 7; }

__device__ __forceinline__ us f2bu(float x) {   // scalar fp32->bf16 (RNE)
    unsigned u = __float_as_uint(x);
    return (us)((u + 0x7FFFu + ((u >> 16) & 1u)) >> 16);
}
__device__ __forceinline__ unsigned pk2(float a, float b) {
    return (unsigned)f2bu(a) | ((unsigned)f2bu(b) << 16);
}
__device__ __forceinline__ bf16x4 pk4(float a, float b, float c, float d) {
    uint2v u; u[0] = pk2(a, b); u[1] = pk2(c, d);
    return __builtin_bit_cast(bf16x4, u);
}

// async 16B global->LDS; lds ptr wave-uniform, lane i lands at lds + i*16.
__device__ __forceinline__ void gll16(const void* g, void* l) {
    __builtin_amdgcn_global_load_lds(
        (const __attribute__((address_space(1))) void*)(void*)g,
        (__attribute__((address_space(3))) void*)l, 16, 0, 0);
}

// ---------------------------------------------------------------------------
// 4x W fp32 [512][512] -> bf16, packed at Wb + m*CC*CC
// ---------------------------------------------------------------------------
__global__ __launch_bounds__(256) void w_cvt(const float* __restrict__ W0,
                                             const float* __restrict__ W1,
                                             const float* __restrict__ W2,
                                             const float* __restrict__ W3,
                                             us* __restrict__ Wb)
{
    const float* Ws[4] = {W0, W1, W2, W3};
    const int m = blockIdx.y;
    const float* W = Ws[m];
    const size_t idx = ((size_t)blockIdx.x * 256 + threadIdx.x) * 8;
    const float4 f0 = *(const float4*)(W + idx);
    const float4 f1 = *(const float4*)(W + idx + 4);
    uint4v u;
    u[0] = pk2(f0.x, f0.y); u[1] = pk2(f0.z, f0.w);
    u[2] = pk2(f1.x, f1.y); u[3] = pk2(f1.z, f1.w);
    *(bf16x8*)(Wb + (size_t)m * CC * CC + idx) = __builtin_bit_cast(bf16x8, u);
}

// ---------------------------------------------------------------------------
// fp32 [b][c][n] -> bf16 [b][n][c]
// ---------------------------------------------------------------------------
__global__ __launch_bounds__(256) void transpose_cvt(const float* __restrict__ X,
                                                     us* __restrict__ Xt)
{
    const int b = blockIdx.z, c0 = blockIdx.y * 64, n0 = blockIdx.x * 64;
    const int t = threadIdx.x;
    __shared__ float T[64][65];

    const float* Xb = X + ((size_t)b * CC + c0) * LL + n0;
    #pragma unroll
    for (int i = 0; i < 4; ++i) {
        const int cl = (t >> 4) + 16 * i, nl = (t & 15) * 4;
        const float4 f = *(const float4*)(Xb + (size_t)cl * LL + nl);
        T[cl][nl + 0] = f.x; T[cl][nl + 1] = f.y;
        T[cl][nl + 2] = f.z; T[cl][nl + 3] = f.w;
    }
    __syncthreads();
    us* Ot = Xt + ((size_t)b * LL + n0) * CC + c0;
    #pragma unroll
    for (int i = 0; i < 2; ++i) {
        const int nl = (t >> 3) + 32 * i, cb = (t & 7) * 8;
        uint4v u;
        #pragma unroll
        for (int j = 0; j < 4; ++j)
            u[j] = pk2(T[cb + 2 * j][nl], T[cb + 2 * j + 1][nl]);
        *(bf16x8*)(Ot + (size_t)nl * CC + cb) = __builtin_bit_cast(bf16x8, u);
    }
}

// ---------------------------------------------------------------------------
// GEMM: Y[b][o][n] = sum_c Wb[o][c]*Xt[b][n][c] + bias[o].
// Tile 64(M) x 128(N), BK=64, 256 thr = 4 waves of 32x64. gll staging.
// ---------------------------------------------------------------------------
template <int MODE>
__global__ __launch_bounds__(256, 4) void proj_gemm(const us* __restrict__ Xt,
                                                    const us* __restrict__ Wb,
                                                    const float* __restrict__ bias,
                                                    float scale,
                                                    void* __restrict__ Yv)
{
    const int b  = blockIdx.z, n0 = blockIdx.x * 128, m0 = blockIdx.y * 64;
    const int t  = threadIdx.x, lane = t & 63, wave = t >> 6;
    const int quad2 = lane >> 5, l31 = lane & 31;
    const int lsub = lane >> 3, lbk = lane & 7;
    const int wm = (wave >> 1) * 32, wn = (wave & 1) * 64;

    __shared__ us As[64 * 64];    // [m][k] swizzled
    __shared__ us Bs[128 * 64];   // [n][k] swizzled
    __shared__ float biasS[64];

    f32x16 acc[2];
    #pragma unroll
    for (int nt = 0; nt < 2; ++nt)
        #pragma unroll
        for (int e = 0; e < 16; ++e) acc[nt][e] = 0.f;

    if (t < 64) biasS[t] = bias[m0 + t];

    const us* Xb = Xt + (size_t)b * LL * CC;

    for (int k0 = 0; k0 < CC; k0 += 64) {
        __syncthreads();
        #pragma unroll
        for (int i = 0; i < 2; ++i) {
            const int rb = i * 32 + wave * 8;
            const int r  = rb + lsub;
            gll16(Wb + (size_t)(m0 + r) * CC + k0 + ((lbk ^ swz(r)) * 8),
                  As + rb * 64);
        }
        #pragma unroll
        for (int i = 0; i < 4; ++i) {
            const int rb = i * 32 + wave * 8;
            const int r  = rb + lsub;
            gll16(Xb + (size_t)(n0 + r) * CC + k0 + ((lbk ^ swz(r)) * 8),
                  Bs + rb * 64);
        }
        __syncthreads();
        #pragma unroll
        for (int ks = 0; ks < 4; ++ks) {
            const int bk = quad2 + 2 * ks;
            const int ra = wm + l31;
            const bf16x8 af = *(const bf16x8*)(As + ra * 64 + ((bk ^ swz(ra)) * 8));
            #pragma unroll
            for (int nt = 0; nt < 2; ++nt) {
                const int rb = wn + nt * 32 + l31;
                const bf16x8 bfr = *(const bf16x8*)(Bs + rb * 64 + ((bk ^ swz(rb)) * 8));
                acc[nt] = __builtin_amdgcn_mfma_f32_32x32x16_bf16(af, bfr, acc[nt], 0, 0, 0);
            }
        }
    }

    #pragma unroll
    for (int nt = 0; nt < 2; ++nt) {
        const int nloc = wn + nt * 32 + l31;
        if (MODE == 0) {
            us* Y = (us*)Yv;
            #pragma unroll
            for (int rg2 = 0; rg2 < 4; ++rg2) {
                const int rbase = wm + 8 * rg2 + 4 * quad2;
                float v0 = (acc[nt][rg2 * 4 + 0] + biasS[rbase + 0]) * scale;
                float v1 = (acc[nt][rg2 * 4 + 1] + biasS[rbase + 1]) * scale;
                float v2 = (acc[nt][rg2 * 4 + 2] + biasS[rbase + 2]) * scale;
                float v3 = (acc[nt][rg2 * 4 + 3] + biasS[rbase + 3]) * scale;
                const int mg = m0 + rbase;
                const int h = mg >> 6, d = mg & 63;
                *(bf16x4*)(Y + (((size_t)(b * HH + h) * LL) + n0 + nloc) * DHH + d) =
                    pk4(v0, v1, v2, v3);
            }
        } else {
            #pragma unroll
            for (int reg = 0; reg < 16; ++reg) {
                const int row = (reg & 3) + 8 * (reg >> 2) + 4 * quad2;
                const int mloc = wm + row;
                const float v = (acc[nt][reg] + biasS[mloc]) * scale;
                const size_t addr = ((size_t)b * CC + m0 + mloc) * LL + n0 + nloc;
                if (MODE == 1) ((us*)Yv)[addr] = f2bu(v);
                else           ((float*)Yv)[addr] = v;
            }
        }
    }
}

// ---------------------------------------------------------------------------
// Flash attention, key-split. Block = 256 thr (4 waves x 32 q). Grid
// (bh=32, qb=16, split=NSPLIT). Each block handles 32/NSPLIT key tiles.
// No-max softmax (linear partial combine). P^T -> PV B-frags via shfl_xor.
// NSPLIT==1: normalize + write ctx. NSPLIT>1: write fp32 O^T partial
// [s][bh][d][q] + l partial [s][bh][q].
// ---------------------------------------------------------------------------
template <int NSPLIT>
__global__ __launch_bounds__(256, 4) void attn_fwd(
    const us* __restrict__ Qh,     // [b][h][l][64], pre-scaled 0.125*log2e
    const us* __restrict__ Kh,     // [b][h][l][64]
    const us* __restrict__ Vh,     // [b][512][l] channel-major
    const float* __restrict__ mask,// [b][1][L]
    us* __restrict__ ctx,          // [b][l][512]        (NSPLIT==1)
    float* __restrict__ Opart,     // [s][bh][64][2048]  (NSPLIT>1)
    float* __restrict__ Lpart)     // [s][bh][2048]      (NSPLIT>1)
{
    const int bh = blockIdx.x;     // 0..31
    const int b = bh >> 3, h = bh & 7;
    const int qb = blockIdx.y;     // 0..15
    const int sp = blockIdx.z;     // 0..NSPLIT-1
    const int t = threadIdx.x, lane = t & 63, wave = t >> 6;
    const int quad2 = lane >> 5, l31 = lane & 31;
    const int qg = qb * 128 + wave * 32;     // wave's query base
    const int tn = 32 / NSPLIT;              // key tiles per block
    const int t0 = sp * tn;

    __shared__ us Ks[2][64 * 64];  // [n][d] swizzled, double-buffered
    __shared__ us Vs[2][64 * 64];  // [d][n] swizzled
    __shared__ unsigned long long mwS[32];

    const float* mb = mask + (size_t)b * LL;
    #pragma unroll
    for (int i = 0; i < 8; ++i) {            // all 32 tile ballots
        const int tile = wave * 8 + i;
        const unsigned long long bal = __ballot(mb[tile * 64 + lane] > 0.5f);
        if (lane == 0) mwS[tile] = bal;
    }

    const us* Qbase = Qh + (size_t)bh * LL * DHH;
    bf16x8 qf[4];
    #pragma unroll
    for (int ks = 0; ks < 4; ++ks)
        qf[ks] = *(const bf16x8*)(Qbase + (size_t)(qg + l31) * DHH + ks * 16 + quad2 * 8);

    f32x16 of[2];
    #pragma unroll
    for (int mt = 0; mt < 2; ++mt)
        #pragma unroll
        for (int e = 0; e < 16; ++e) of[mt][e] = 0.f;
    float l_run = 0.f;

    const us* Kbase = Kh + (size_t)bh * LL * DHH;
    const us* Vbase = Vh + ((size_t)b * CC + h * DHH) * LL;

    // stage tile t0 into buffer 0
    #pragma unroll
    for (int i = 0; i < 2; ++i) {
        const int id = i * 256 + t;
        const int r = id >> 3, bk = id & 7;
        *(bf16x8*)(Ks[0] + r * 64 + ((bk ^ swz(r)) * 8)) =
            *(const bf16x8*)(Kbase + (size_t)(t0 * 64 + r) * DHH + bk * 8);
        *(bf16x8*)(Vs[0] + r * 64 + ((bk ^ swz(r)) * 8)) =
            *(const bf16x8*)(Vbase + (size_t)r * LL + t0 * 64 + bk * 8);
    }
    __syncthreads();

    for (int ii = 0; ii < tn; ++ii) {
        const int it = t0 + ii;
        const int cur = ii & 1;

        // prefetch next K/V tile into registers
        bf16x8 kpre[2], vpre[2];
        if (ii + 1 < tn) {
            const int n1 = (it + 1) * 64;
            #pragma unroll
            for (int i = 0; i < 2; ++i) {
                const int id = i * 256 + t;
                const int r = id >> 3, bk = id & 7;
                kpre[i] = *(const bf16x8*)(Kbase + (size_t)(n1 + r) * DHH + bk * 8);
                vpre[i] = *(const bf16x8*)(Vbase + (size_t)r * LL + n1 + bk * 8);
            }
        }

        // S^T = K^T Q
        f32x16 sf[2];
        #pragma unroll
        for (int mt = 0; mt < 2; ++mt)
            #pragma unroll
            for (int e = 0; e < 16; ++e) sf[mt][e] = 0.f;
        #pragma unroll
        for (int ks = 0; ks < 4; ++ks) {
            const int bk = quad2 + 2 * ks;
            #pragma unroll
            for (int mt = 0; mt < 2; ++mt) {
                const int r = mt * 32 + l31;
                const bf16x8 af = *(const bf16x8*)(Ks[cur] + r * 64 + ((bk ^ swz(r)) * 8));
                sf[mt] = __builtin_amdgcn_mfma_f32_32x32x16_bf16(af, qf[ks], sf[mt], 0, 0, 0);
            }
        }

        // no-max softmax + pack + shfl exchange into PV B-fragments
        const unsigned long long mw = mwS[it];
        bf16x8 pf[4];
        float ps = 0.f;
        #pragma unroll
        for (int mt = 0; mt < 2; ++mt) {
            float p[16];
            #pragma unroll
            for (int rg2 = 0; rg2 < 4; ++rg2)
                #pragma unroll
                for (int j = 0; j < 4; ++j) {
                    const int e = rg2 * 4 + j;
                    float pv = EXP2(sf[mt][e]);
                    if (mw != 0xFFFFFFFFFFFFFFFFull) {
                        const int row = 32 * mt + 8 * rg2 + 4 * quad2 + j;
                        pv = ((mw >> row) & 1ull) ? pv : 0.f;
                    }
                    p[e] = pv;
                    ps += pv;
                }
            #pragma unroll
            for (int ksl = 0; ksl < 2; ++ksl) {
                const int base_o = 8 * ksl + 4 * quad2;        // own-q2t group
                const int base_x = 8 * ksl + 4 * (1 - quad2);  // partner's need
                const unsigned do0 = pk2(p[base_o + 0], p[base_o + 1]);
                const unsigned do1 = pk2(p[base_o + 2], p[base_o + 3]);
                const unsigned dx0 = pk2(p[base_x + 0], p[base_x + 1]);
                const unsigned dx1 = pk2(p[base_x + 2], p[base_x + 3]);
                const unsigned rx0 = (unsigned)__shfl_xor((int)dx0, 32, 64);
                const unsigned rx1 = (unsigned)__shfl_xor((int)dx1, 32, 64);
                uint4v u;
                if (quad2 == 0) { u[0] = do0; u[1] = do1; u[2] = rx0; u[3] = rx1; }
                else            { u[0] = rx0; u[1] = rx1; u[2] = do0; u[3] = do1; }
                pf[2 * mt + ksl] = __builtin_bit_cast(bf16x8, u);
            }
        }
        ps += __shfl_xor(ps, 32, 64);
        l_run += ps;

        // O^T += V P^T
        #pragma unroll
        for (int ks = 0; ks < 4; ++ks) {
            const int bk = quad2 + 2 * ks;
            #pragma unroll
            for (int mt = 0; mt < 2; ++mt) {
                const int r = mt * 32 + l31;
                const bf16x8 vf = *(const bf16x8*)(Vs[cur] + r * 64 + ((bk ^ swz(r)) * 8));
                of[mt] = __builtin_amdgcn_mfma_f32_32x32x16_bf16(vf, pf[ks], of[mt], 0, 0, 0);
            }
        }

        // write prefetched tile to the alternate buffer
        if (ii + 1 < tn) {
            #pragma unroll
            for (int i = 0; i < 2; ++i) {
                const int id = i * 256 + t;
                const int r = id >> 3, bk = id & 7;
                *(bf16x8*)(Ks[1 - cur] + r * 64 + ((bk ^ swz(r)) * 8)) = kpre[i];
                *(bf16x8*)(Vs[1 - cur] + r * 64 + ((bk ^ swz(r)) * 8)) = vpre[i];
            }
        }
        __syncthreads();
    }

    if (NSPLIT == 1) {
        // normalize + write ctx[b][q][h*64+d]
        us* Cb = ctx + (size_t)b * LL * CC;
        const float inv = 1.0f / l_run;
        const int q = qg + l31;
        #pragma unroll
        for (int mt = 0; mt < 2; ++mt)
            #pragma unroll
            for (int rg2 = 0; rg2 < 4; ++rg2) {
                const int d = 32 * mt + 8 * rg2 + 4 * quad2;
                *(bf16x4*)(Cb + (size_t)q * CC + h * DHH + d) =
                    pk4(of[mt][rg2 * 4 + 0] * inv, of[mt][rg2 * 4 + 1] * inv,
                        of[mt][rg2 * 4 + 2] * inv, of[mt][rg2 * 4 + 3] * inv);
            }
    } else {
        // unnormalized partials
        float* Ob = Opart + (size_t)(sp * 32 + bh) * DHH * LL;
        #pragma unroll
        for (int mt = 0; mt < 2; ++mt)
            #pragma unroll
            for (int rg2 = 0; rg2 < 4; ++rg2)
                #pragma unroll
                for (int j = 0; j < 4; ++j) {
                    const int d = 32 * mt + 8 * rg2 + 4 * quad2 + j;
                    Ob[(size_t)d * LL + qg + l31] = of[mt][rg2 * 4 + j];
                }
        if (lane < 32)
            Lpart[(size_t)(sp * 32 + bh) * LL + qg + l31] = l_run;
    }
}

// ---------------------------------------------------------------------------
// Combine key-split partials: ctx[b][q][h*64+d] = sum_s O / sum_s l
// ---------------------------------------------------------------------------
__global__ __launch_bounds__(256) void attn_reduce(const float* __restrict__ Opart,
                                                   const float* __restrict__ Lpart,
                                                   us* __restrict__ ctx)
{
    const int bh = blockIdx.x, b = bh >> 3, h = bh & 7;
    const int q0 = blockIdx.y * 64;
    const int t = threadIdx.x;
    __shared__ float T[64][65];
    __shared__ float lS[64];

    if (t < 64)
        lS[t] = 1.0f / (Lpart[(size_t)bh * LL + q0 + t] +
                        Lpart[(size_t)(32 + bh) * LL + q0 + t]);

    const float* O0 = Opart + (size_t)bh * DHH * LL;
    const float* O1 = Opart + (size_t)(32 + bh) * DHH * LL;
    #pragma unroll
    for (int i = 0; i < 4; ++i) {
        const int id = i * 256 + t;
        const int d = id >> 4, f4 = (id & 15) * 4;
        const float4 a = *(const float4*)(O0 + (size_t)d * LL + q0 + f4);
        const float4 c = *(const float4*)(O1 + (size_t)d * LL + q0 + f4);
        T[d][f4 + 0] = a.x + c.x; T[d][f4 + 1] = a.y + c.y;
        T[d][f4 + 2] = a.z + c.z; T[d][f4 + 3] = a.w + c.w;
    }
    __syncthreads();
    #pragma unroll
    for (int i = 0; i < 2; ++i) {
        const int id = i * 256 + t;
        const int qq = id >> 3, d0 = (id & 7) * 8;
        const float inv = lS[qq];
        uint4v u;
        #pragma unroll
        for (int j = 0; j < 4; ++j)
            u[j] = pk2(T[d0 + 2 * j][qq] * inv, T[d0 + 2 * j + 1][qq] * inv);
        *(bf16x8*)(ctx + ((size_t)(b * LL + q0 + qq)) * CC + h * DHH + d0) =
            __builtin_bit_cast(bf16x8, u);
    }
}

// ---------------------------------------------------------------------------
extern "C" void kernel_launch(void* const* d_in, const int* in_sizes, int n_in,
                              void* d_out, int out_size, void* d_ws, size_t ws_size,
                              hipStream_t stream)
{
    const float* q    = (const float*)d_in[0];
    const float* k    = (const float*)d_in[1];
    const float* v    = (const float*)d_in[2];
    const float* mask = (const float*)d_in[3];
    const float* Wq   = (const float*)d_in[4];
    const float* bq   = (const float*)d_in[5];
    const float* Wk   = (const float*)d_in[6];
    const float* bk   = (const float*)d_in[7];
    const float* Wv   = (const float*)d_in[8];
    const float* bv   = (const float*)d_in[9];
    const float* Wout = (const float*)d_in[10];
    const float* bout = (const float*)d_in[11];

    const size_t TSZ = (size_t)BB * CC * LL;   // 4,194,304 elements (8 MB bf16)
    us* base = (us*)d_ws;
    us* Xt   = base;                // [0,8M)  also ctx after v-proj
    us* kh   = base + TSZ;          // [8M,16M)
    us* vh   = base + 2 * TSZ;      // [16M,24M)
    us* Wb   = base + 3 * TSZ;      // [24M,26M): 4 x 512x512 bf16
    us* ctx  = Xt;
    us* qh   = (us*)d_out;          // d_out (16MB fp32) dead until out-proj

    float* Opart = (float*)(Wb + 4 * CC * CC);           // 33.5 MB
    float* Lpart = Opart + (size_t)2 * 32 * DHH * LL;    // 0.5 MB
    const size_t ws_need = (size_t)(Wb + 4 * CC * CC - base) * 2  // 26 MB
                         + (size_t)2 * 32 * DHH * LL * 4          // Opart
                         + (size_t)2 * 32 * LL * 4;               // Lpart
    const bool split = ws_size >= ws_need;

    const float SCALE_Q = 0.125f * 1.4426950408889634f;  // softmax scale * log2e

    const dim3 wg(CC * CC / (256 * 8), 4);
    const dim3 tg(LL / 64, CC / 64, BB), tb(256);
    const dim3 gg(LL / 128, CC / 64, BB), gb(256);

    w_cvt<<<wg, 256, 0, stream>>>(Wq, Wk, Wv, Wout, Wb);

    transpose_cvt<<<tg, tb, 0, stream>>>(q, Xt);
    proj_gemm<0><<<gg, gb, 0, stream>>>(Xt, Wb + 0 * CC * CC, bq, SCALE_Q, (void*)qh);
    transpose_cvt<<<tg, tb, 0, stream>>>(k, Xt);
    proj_gemm<0><<<gg, gb, 0, stream>>>(Xt, Wb + 1 * CC * CC, bk, 1.0f, (void*)kh);
    transpose_cvt<<<tg, tb, 0, stream>>>(v, Xt);
    proj_gemm<1><<<gg, gb, 0, stream>>>(Xt, Wb + 2 * CC * CC, bv, 1.0f, (void*)vh);

    if (split) {
        attn_fwd<2><<<dim3(HH * BB, LL / 128, 2), 256, 0, stream>>>(
            qh, kh, vh, mask, ctx, Opart, Lpart);
        attn_reduce<<<dim3(HH * BB, LL / 64), 256, 0, stream>>>(Opart, Lpart, ctx);
    } else {
        attn_fwd<1><<<dim3(HH * BB, LL / 128, 1), 256, 0, stream>>>(
            qh, kh, vh, mask, ctx, Opart, Lpart);
    }

    proj_gemm<2><<<gg, gb, 0, stream>>>(ctx, Wb + 3 * CC * CC, bout, 1.0f, d_out);
}

// Round 10
// 310.473 us; speedup vs baseline: 1.9113x; 1.9113x over previous
//
#include <hip/hip_runtime.h>
#include <hip/hip_bf16.h>

// LocalAttention B=4, L=2048, C=512, H=8, Dh=64 — round 10.
// r9 with ONE change: attn launch_bounds (256,4) -> (256,2). r9's (,4)
// capped VGPR at 128 < ~160 live -> ~40 regs spilled/lane/tile -> 1.17 GB
// scratch HBM traffic (matched arithmetic). (,2) lets the allocator land
// ~130 VGPR (r8: 124) -> no spill, 3-4 waves/SIMD via the 2-way key split.

#define BB  4
#define LL  2048
#define CC  512
#define HH  8
#define DHH 64

typedef __attribute__((ext_vector_type(8)))  short bf16x8;   // 16 B
typedef __attribute__((ext_vector_type(4)))  short bf16x4;   // 8 B
typedef __attribute__((ext_vector_type(16))) float f32x16;   // MFMA C/D
typedef __attribute__((ext_vector_type(2)))  unsigned uint2v;
typedef __attribute__((ext_vector_type(4)))  unsigned uint4v;

using us = unsigned short;

#if __has_builtin(__builtin_amdgcn_exp2f)
#define EXP2(x) __builtin_amdgcn_exp2f(x)
#else
#define EXP2(x) __expf(0.6931471805599453f * (x))
#endif

__device__ __forceinline__ int swz(int r) { return (r + (r >> 3)) & 7; }

__device__ __forceinline__ us f2bu(float x) {   // scalar fp32->bf16 (RNE)
    unsigned u = __float_as_uint(x);
    return (us)((u + 0x7FFFu + ((u >> 16) & 1u)) >> 16);
}
__device__ __forceinline__ unsigned pk2(float a, float b) {
    return (unsigned)f2bu(a) | ((unsigned)f2bu(b) << 16);
}
__device__ __forceinline__ bf16x4 pk4(float a, float b, float c, float d) {
    uint2v u; u[0] = pk2(a, b); u[1] = pk2(c, d);
    return __builtin_bit_cast(bf16x4, u);
}

// async 16B global->LDS; lds ptr wave-uniform, lane i lands at lds + i*16.
__device__ __forceinline__ void gll16(const void* g, void* l) {
    __builtin_amdgcn_global_load_lds(
        (const __attribute__((address_space(1))) void*)(void*)g,
        (__attribute__((address_space(3))) void*)l, 16, 0, 0);
}

// ---------------------------------------------------------------------------
// 4x W fp32 [512][512] -> bf16, packed at Wb + m*CC*CC
// ---------------------------------------------------------------------------
__global__ __launch_bounds__(256) void w_cvt(const float* __restrict__ W0,
                                             const float* __restrict__ W1,
                                             const float* __restrict__ W2,
                                             const float* __restrict__ W3,
                                             us* __restrict__ Wb)
{
    const float* Ws[4] = {W0, W1, W2, W3};
    const int m = blockIdx.y;
    const float* W = Ws[m];
    const size_t idx = ((size_t)blockIdx.x * 256 + threadIdx.x) * 8;
    const float4 f0 = *(const float4*)(W + idx);
    const float4 f1 = *(const float4*)(W + idx + 4);
    uint4v u;
    u[0] = pk2(f0.x, f0.y); u[1] = pk2(f0.z, f0.w);
    u[2] = pk2(f1.x, f1.y); u[3] = pk2(f1.z, f1.w);
    *(bf16x8*)(Wb + (size_t)m * CC * CC + idx) = __builtin_bit_cast(bf16x8, u);
}

// ---------------------------------------------------------------------------
// fp32 [b][c][n] -> bf16 [b][n][c]
// ---------------------------------------------------------------------------
__global__ __launch_bounds__(256) void transpose_cvt(const float* __restrict__ X,
                                                     us* __restrict__ Xt)
{
    const int b = blockIdx.z, c0 = blockIdx.y * 64, n0 = blockIdx.x * 64;
    const int t = threadIdx.x;
    __shared__ float T[64][65];

    const float* Xb = X + ((size_t)b * CC + c0) * LL + n0;
    #pragma unroll
    for (int i = 0; i < 4; ++i) {
        const int cl = (t >> 4) + 16 * i, nl = (t & 15) * 4;
        const float4 f = *(const float4*)(Xb + (size_t)cl * LL + nl);
        T[cl][nl + 0] = f.x; T[cl][nl + 1] = f.y;
        T[cl][nl + 2] = f.z; T[cl][nl + 3] = f.w;
    }
    __syncthreads();
    us* Ot = Xt + ((size_t)b * LL + n0) * CC + c0;
    #pragma unroll
    for (int i = 0; i < 2; ++i) {
        const int nl = (t >> 3) + 32 * i, cb = (t & 7) * 8;
        uint4v u;
        #pragma unroll
        for (int j = 0; j < 4; ++j)
            u[j] = pk2(T[cb + 2 * j][nl], T[cb + 2 * j + 1][nl]);
        *(bf16x8*)(Ot + (size_t)nl * CC + cb) = __builtin_bit_cast(bf16x8, u);
    }
}

// ---------------------------------------------------------------------------
// GEMM: Y[b][o][n] = sum_c Wb[o][c]*Xt[b][n][c] + bias[o].
// Tile 64(M) x 128(N), BK=64, 256 thr = 4 waves of 32x64. gll staging.
// ---------------------------------------------------------------------------
template <int MODE>
__global__ __launch_bounds__(256, 4) void proj_gemm(const us* __restrict__ Xt,
                                                    const us* __restrict__ Wb,
                                                    const float* __restrict__ bias,
                                                    float scale,
                                                    void* __restrict__ Yv)
{
    const int b  = blockIdx.z, n0 = blockIdx.x * 128, m0 = blockIdx.y * 64;
    const int t  = threadIdx.x, lane = t & 63, wave = t >> 6;
    const int quad2 = lane >> 5, l31 = lane & 31;
    const int lsub = lane >> 3, lbk = lane & 7;
    const int wm = (wave >> 1) * 32, wn = (wave & 1) * 64;

    __shared__ us As[64 * 64];    // [m][k] swizzled
    __shared__ us Bs[128 * 64];   // [n][k] swizzled
    __shared__ float biasS[64];

    f32x16 acc[2];
    #pragma unroll
    for (int nt = 0; nt < 2; ++nt)
        #pragma unroll
        for (int e = 0; e < 16; ++e) acc[nt][e] = 0.f;

    if (t < 64) biasS[t] = bias[m0 + t];

    const us* Xb = Xt + (size_t)b * LL * CC;

    for (int k0 = 0; k0 < CC; k0 += 64) {
        __syncthreads();
        #pragma unroll
        for (int i = 0; i < 2; ++i) {
            const int rb = i * 32 + wave * 8;
            const int r  = rb + lsub;
            gll16(Wb + (size_t)(m0 + r) * CC + k0 + ((lbk ^ swz(r)) * 8),
                  As + rb * 64);
        }
        #pragma unroll
        for (int i = 0; i < 4; ++i) {
            const int rb = i * 32 + wave * 8;
            const int r  = rb + lsub;
            gll16(Xb + (size_t)(n0 + r) * CC + k0 + ((lbk ^ swz(r)) * 8),
                  Bs + rb * 64);
        }
        __syncthreads();
        #pragma unroll
        for (int ks = 0; ks < 4; ++ks) {
            const int bk = quad2 + 2 * ks;
            const int ra = wm + l31;
            const bf16x8 af = *(const bf16x8*)(As + ra * 64 + ((bk ^ swz(ra)) * 8));
            #pragma unroll
            for (int nt = 0; nt < 2; ++nt) {
                const int rb = wn + nt * 32 + l31;
                const bf16x8 bfr = *(const bf16x8*)(Bs + rb * 64 + ((bk ^ swz(rb)) * 8));
                acc[nt] = __builtin_amdgcn_mfma_f32_32x32x16_bf16(af, bfr, acc[nt], 0, 0, 0);
            }
        }
    }

    #pragma unroll
    for (int nt = 0; nt < 2; ++nt) {
        const int nloc = wn + nt * 32 + l31;
        if (MODE == 0) {
            us* Y = (us*)Yv;
            #pragma unroll
            for (int rg2 = 0; rg2 < 4; ++rg2) {
                const int rbase = wm + 8 * rg2 + 4 * quad2;
                float v0 = (acc[nt][rg2 * 4 + 0] + biasS[rbase + 0]) * scale;
                float v1 = (acc[nt][rg2 * 4 + 1] + biasS[rbase + 1]) * scale;
                float v2 = (acc[nt][rg2 * 4 + 2] + biasS[rbase + 2]) * scale;
                float v3 = (acc[nt][rg2 * 4 + 3] + biasS[rbase + 3]) * scale;
                const int mg = m0 + rbase;
                const int h = mg >> 6, d = mg & 63;
                *(bf16x4*)(Y + (((size_t)(b * HH + h) * LL) + n0 + nloc) * DHH + d) =
                    pk4(v0, v1, v2, v3);
            }
        } else {
            #pragma unroll
            for (int reg = 0; reg < 16; ++reg) {
                const int row = (reg & 3) + 8 * (reg >> 2) + 4 * quad2;
                const int mloc = wm + row;
                const float v = (acc[nt][reg] + biasS[mloc]) * scale;
                const size_t addr = ((size_t)b * CC + m0 + mloc) * LL + n0 + nloc;
                if (MODE == 1) ((us*)Yv)[addr] = f2bu(v);
                else           ((float*)Yv)[addr] = v;
            }
        }
    }
}

// ---------------------------------------------------------------------------
// Flash attention, key-split. Block = 256 thr (4 waves x 32 q). Grid
// (bh=32, qb=16, split=NSPLIT). No-max softmax (linear combine). shfl P
// exchange. launch_bounds (256,2): allocator needs ~130-160 VGPR — capping
// at 128 (r9's (,4)) caused 1.17 GB of scratch spill traffic.
// ---------------------------------------------------------------------------
template <int NSPLIT>
__global__ __launch_bounds__(256, 2) void attn_fwd(
    const us* __restrict__ Qh,     // [b][h][l][64], pre-scaled 0.125*log2e
    const us* __restrict__ Kh,     // [b][h][l][64]
    const us* __restrict__ Vh,     // [b][512][l] channel-major
    const float* __restrict__ mask,// [b][1][L]
    us* __restrict__ ctx,          // [b][l][512]        (NSPLIT==1)
    float* __restrict__ Opart,     // [s][bh][64][2048]  (NSPLIT>1)
    float* __restrict__ Lpart)     // [s][bh][2048]      (NSPLIT>1)
{
    const int bh = blockIdx.x;     // 0..31
    const int b = bh >> 3, h = bh & 7;
    const int qb = blockIdx.y;     // 0..15
    const int sp = blockIdx.z;     // 0..NSPLIT-1
    const int t = threadIdx.x, lane = t & 63, wave = t >> 6;
    const int quad2 = lane >> 5, l31 = lane & 31;
    const int qg = qb * 128 + wave * 32;     // wave's query base
    const int tn = 32 / NSPLIT;              // key tiles per block
    const int t0 = sp * tn;

    __shared__ us Ks[2][64 * 64];  // [n][d] swizzled, double-buffered
    __shared__ us Vs[2][64 * 64];  // [d][n] swizzled
    __shared__ unsigned long long mwS[32];

    const float* mb = mask + (size_t)b * LL;
    #pragma unroll
    for (int i = 0; i < 8; ++i) {            // all 32 tile ballots
        const int tile = wave * 8 + i;
        const unsigned long long bal = __ballot(mb[tile * 64 + lane] > 0.5f);
        if (lane == 0) mwS[tile] = bal;
    }

    const us* Qbase = Qh + (size_t)bh * LL * DHH;
    bf16x8 qf[4];
    #pragma unroll
    for (int ks = 0; ks < 4; ++ks)
        qf[ks] = *(const bf16x8*)(Qbase + (size_t)(qg + l31) * DHH + ks * 16 + quad2 * 8);

    f32x16 of[2];
    #pragma unroll
    for (int mt = 0; mt < 2; ++mt)
        #pragma unroll
        for (int e = 0; e < 16; ++e) of[mt][e] = 0.f;
    float l_run = 0.f;

    const us* Kbase = Kh + (size_t)bh * LL * DHH;
    const us* Vbase = Vh + ((size_t)b * CC + h * DHH) * LL;

    // stage tile t0 into buffer 0
    #pragma unroll
    for (int i = 0; i < 2; ++i) {
        const int id = i * 256 + t;
        const int r = id >> 3, bk = id & 7;
        *(bf16x8*)(Ks[0] + r * 64 + ((bk ^ swz(r)) * 8)) =
            *(const bf16x8*)(Kbase + (size_t)(t0 * 64 + r) * DHH + bk * 8);
        *(bf16x8*)(Vs[0] + r * 64 + ((bk ^ swz(r)) * 8)) =
            *(const bf16x8*)(Vbase + (size_t)r * LL + t0 * 64 + bk * 8);
    }
    __syncthreads();

    for (int ii = 0; ii < tn; ++ii) {
        const int it = t0 + ii;
        const int cur = ii & 1;

        // prefetch next K/V tile into registers
        bf16x8 kpre[2], vpre[2];
        if (ii + 1 < tn) {
            const int n1 = (it + 1) * 64;
            #pragma unroll
            for (int i = 0; i < 2; ++i) {
                const int id = i * 256 + t;
                const int r = id >> 3, bk = id & 7;
                kpre[i] = *(const bf16x8*)(Kbase + (size_t)(n1 + r) * DHH + bk * 8);
                vpre[i] = *(const bf16x8*)(Vbase + (size_t)r * LL + n1 + bk * 8);
            }
        }

        // S^T = K^T Q
        f32x16 sf[2];
        #pragma unroll
        for (int mt = 0; mt < 2; ++mt)
            #pragma unroll
            for (int e = 0; e < 16; ++e) sf[mt][e] = 0.f;
        #pragma unroll
        for (int ks = 0; ks < 4; ++ks) {
            const int bk = quad2 + 2 * ks;
            #pragma unroll
            for (int mt = 0; mt < 2; ++mt) {
                const int r = mt * 32 + l31;
                const bf16x8 af = *(const bf16x8*)(Ks[cur] + r * 64 + ((bk ^ swz(r)) * 8));
                sf[mt] = __builtin_amdgcn_mfma_f32_32x32x16_bf16(af, qf[ks], sf[mt], 0, 0, 0);
            }
        }

        // no-max softmax + pack + shfl exchange into PV B-fragments
        const unsigned long long mw = mwS[it];
        bf16x8 pf[4];
        float ps = 0.f;
        #pragma unroll
        for (int mt = 0; mt < 2; ++mt) {
            float p[16];
            #pragma unroll
            for (int rg2 = 0; rg2 < 4; ++rg2)
                #pragma unroll
                for (int j = 0; j < 4; ++j) {
                    const int e = rg2 * 4 + j;
                    float pv = EXP2(sf[mt][e]);
                    if (mw != 0xFFFFFFFFFFFFFFFFull) {
                        const int row = 32 * mt + 8 * rg2 + 4 * quad2 + j;
                        pv = ((mw >> row) & 1ull) ? pv : 0.f;
                    }
                    p[e] = pv;
                    ps += pv;
                }
            #pragma unroll
            for (int ksl = 0; ksl < 2; ++ksl) {
                const int base_o = 8 * ksl + 4 * quad2;        // own-q2t group
                const int base_x = 8 * ksl + 4 * (1 - quad2);  // partner's need
                const unsigned do0 = pk2(p[base_o + 0], p[base_o + 1]);
                const unsigned do1 = pk2(p[base_o + 2], p[base_o + 3]);
                const unsigned dx0 = pk2(p[base_x + 0], p[base_x + 1]);
                const unsigned dx1 = pk2(p[base_x + 2], p[base_x + 3]);
                const unsigned rx0 = (unsigned)__shfl_xor((int)dx0, 32, 64);
                const unsigned rx1 = (unsigned)__shfl_xor((int)dx1, 32, 64);
                uint4v u;
                if (quad2 == 0) { u[0] = do0; u[1] = do1; u[2] = rx0; u[3] = rx1; }
                else            { u[0] = rx0; u[1] = rx1; u[2] = do0; u[3] = do1; }
                pf[2 * mt + ksl] = __builtin_bit_cast(bf16x8, u);
            }
        }
        ps += __shfl_xor(ps, 32, 64);
        l_run += ps;

        // O^T += V P^T
        #pragma unroll
        for (int ks = 0; ks < 4; ++ks) {
            const int bk = quad2 + 2 * ks;
            #pragma unroll
            for (int mt = 0; mt < 2; ++mt) {
                const int r = mt * 32 + l31;
                const bf16x8 vf = *(const bf16x8*)(Vs[cur] + r * 64 + ((bk ^ swz(r)) * 8));
                of[mt] = __builtin_amdgcn_mfma_f32_32x32x16_bf16(vf, pf[ks], of[mt], 0, 0, 0);
            }
        }

        // write prefetched tile to the alternate buffer
        if (ii + 1 < tn) {
            #pragma unroll
            for (int i = 0; i < 2; ++i) {
                const int id = i * 256 + t;
                const int r = id >> 3, bk = id & 7;
                *(bf16x8*)(Ks[1 - cur] + r * 64 + ((bk ^ swz(r)) * 8)) = kpre[i];
                *(bf16x8*)(Vs[1 - cur] + r * 64 + ((bk ^ swz(r)) * 8)) = vpre[i];
            }
        }
        __syncthreads();
    }

    if (NSPLIT == 1) {
        // normalize + write ctx[b][q][h*64+d]
        us* Cb = ctx + (size_t)b * LL * CC;
        const float inv = 1.0f / l_run;
        const int q = qg + l31;
        #pragma unroll
        for (int mt = 0; mt < 2; ++mt)
            #pragma unroll
            for (int rg2 = 0; rg2 < 4; ++rg2) {
                const int d = 32 * mt + 8 * rg2 + 4 * quad2;
                *(bf16x4*)(Cb + (size_t)q * CC + h * DHH + d) =
                    pk4(of[mt][rg2 * 4 + 0] * inv, of[mt][rg2 * 4 + 1] * inv,
                        of[mt][rg2 * 4 + 2] * inv, of[mt][rg2 * 4 + 3] * inv);
            }
    } else {
        // unnormalized partials
        float* Ob = Opart + (size_t)(sp * 32 + bh) * DHH * LL;
        #pragma unroll
        for (int mt = 0; mt < 2; ++mt)
            #pragma unroll
            for (int rg2 = 0; rg2 < 4; ++rg2)
                #pragma unroll
                for (int j = 0; j < 4; ++j) {
                    const int d = 32 * mt + 8 * rg2 + 4 * quad2 + j;
                    Ob[(size_t)d * LL + qg + l31] = of[mt][rg2 * 4 + j];
                }
        if (lane < 32)
            Lpart[(size_t)(sp * 32 + bh) * LL + qg + l31] = l_run;
    }
}

// ---------------------------------------------------------------------------
// Combine key-split partials: ctx[b][q][h*64+d] = sum_s O / sum_s l
// ---------------------------------------------------------------------------
__global__ __launch_bounds__(256) void attn_reduce(const float* __restrict__ Opart,
                                                   const float* __restrict__ Lpart,
                                                   us* __restrict__ ctx)
{
    const int bh = blockIdx.x, b = bh >> 3, h = bh & 7;
    const int q0 = blockIdx.y * 64;
    const int t = threadIdx.x;
    __shared__ float T[64][65];
    __shared__ float lS[64];

    if (t < 64)
        lS[t] = 1.0f / (Lpart[(size_t)bh * LL + q0 + t] +
                        Lpart[(size_t)(32 + bh) * LL + q0 + t]);

    const float* O0 = Opart + (size_t)bh * DHH * LL;
    const float* O1 = Opart + (size_t)(32 + bh) * DHH * LL;
    #pragma unroll
    for (int i = 0; i < 4; ++i) {
        const int id = i * 256 + t;
        const int d = id >> 4, f4 = (id & 15) * 4;
        const float4 a = *(const float4*)(O0 + (size_t)d * LL + q0 + f4);
        const float4 c = *(const float4*)(O1 + (size_t)d * LL + q0 + f4);
        T[d][f4 + 0] = a.x + c.x; T[d][f4 + 1] = a.y + c.y;
        T[d][f4 + 2] = a.z + c.z; T[d][f4 + 3] = a.w + c.w;
    }
    __syncthreads();
    #pragma unroll
    for (int i = 0; i < 2; ++i) {
        const int id = i * 256 + t;
        const int qq = id >> 3, d0 = (id & 7) * 8;
        const float inv = lS[qq];
        uint4v u;
        #pragma unroll
        for (int j = 0; j < 4; ++j)
            u[j] = pk2(T[d0 + 2 * j][qq] * inv, T[d0 + 2 * j + 1][qq] * inv);
        *(bf16x8*)(ctx + ((size_t)(b * LL + q0 + qq)) * CC + h * DHH + d0) =
            __builtin_bit_cast(bf16x8, u);
    }
}

// ---------------------------------------------------------------------------
extern "C" void kernel_launch(void* const* d_in, const int* in_sizes, int n_in,
                              void* d_out, int out_size, void* d_ws, size_t ws_size,
                              hipStream_t stream)
{
    const float* q    = (const float*)d_in[0];
    const float* k    = (const float*)d_in[1];
    const float* v    = (const float*)d_in[2];
    const float* mask = (const float*)d_in[3];
    const float* Wq   = (const float*)d_in[4];
    const float* bq   = (const float*)d_in[5];
    const float* Wk   = (const float*)d_in[6];
    const float* bk   = (const float*)d_in[7];
    const float* Wv   = (const float*)d_in[8];
    const float* bv   = (const float*)d_in[9];
    const float* Wout = (const float*)d_in[10];
    const float* bout = (const float*)d_in[11];

    const size_t TSZ = (size_t)BB * CC * LL;   // 4,194,304 elements (8 MB bf16)
    us* base = (us*)d_ws;
    us* Xt   = base;                // [0,8M)  also ctx after v-proj
    us* kh   = base + TSZ;          // [8M,16M)
    us* vh   = base + 2 * TSZ;      // [16M,24M)
    us* Wb   = base + 3 * TSZ;      // [24M,26M): 4 x 512x512 bf16
    us* ctx  = Xt;
    us* qh   = (us*)d_out;          // d_out (16MB fp32) dead until out-proj

    float* Opart = (float*)(Wb + 4 * CC * CC);           // 33.5 MB
    float* Lpart = Opart + (size_t)2 * 32 * DHH * LL;    // 0.5 MB
    const size_t ws_need = (size_t)(Wb + 4 * CC * CC - base) * 2  // 26 MB
                         + (size_t)2 * 32 * DHH * LL * 4          // Opart
                         + (size_t)2 * 32 * LL * 4;               // Lpart
    const bool split = ws_size >= ws_need;

    const float SCALE_Q = 0.125f * 1.4426950408889634f;  // softmax scale * log2e

    const dim3 wg(CC * CC / (256 * 8), 4);
    const dim3 tg(LL / 64, CC / 64, BB), tb(256);
    const dim3 gg(LL / 128, CC / 64, BB), gb(256);

    w_cvt<<<wg, 256, 0, stream>>>(Wq, Wk, Wv, Wout, Wb);

    transpose_cvt<<<tg, tb, 0, stream>>>(q, Xt);
    proj_gemm<0><<<gg, gb, 0, stream>>>(Xt, Wb + 0 * CC * CC, bq, SCALE_Q, (void*)qh);
    transpose_cvt<<<tg, tb, 0, stream>>>(k, Xt);
    proj_gemm<0><<<gg, gb, 0, stream>>>(Xt, Wb + 1 * CC * CC, bk, 1.0f, (void*)kh);
    transpose_cvt<<<tg, tb, 0, stream>>>(v, Xt);
    proj_gemm<1><<<gg, gb, 0, stream>>>(Xt, Wb + 2 * CC * CC, bv, 1.0f, (void*)vh);

    if (split) {
        attn_fwd<2><<<dim3(HH * BB, LL / 128, 2), 256, 0, stream>>>(
            qh, kh, vh, mask, ctx, Opart, Lpart);
        attn_reduce<<<dim3(HH * BB, LL / 64), 256, 0, stream>>>(Opart, Lpart, ctx);
    } else {
        attn_fwd<1><<<dim3(HH * BB, LL / 128, 1), 256, 0, stream>>>(
            qh, kh, vh, mask, ctx, Opart, Lpart);
    }

    proj_gemm<2><<<gg, gb, 0, stream>>>(ctx, Wb + 3 * CC * CC, bout, 1.0f, d_out);
}